// Round 2
// baseline (217.433 us; speedup 1.0000x reference)
//
#include <hip/hip_runtime.h>
#include <math.h>

#define NH 8
#define HD 48
#define C_DIM 384
#define C3 1152

// ---------------------------------------------------------------------------
// Tiled fp32 GEMM: C[M,N] = A[M,K] * B[K,N] (+ bias per column, optional)
// BM=BN=64, BK=16, 256 threads, 4x4 micro-tile per thread.
// ---------------------------------------------------------------------------
__global__ __launch_bounds__(256) void gemm64(const float* __restrict__ A,
                                              const float* __restrict__ B,
                                              const float* __restrict__ bias,
                                              float* __restrict__ C,
                                              int M, int N, int K)
{
    __shared__ float As[64][17];   // +1 pad breaks bank-conflict on column reads
    __shared__ float Bs[16][64];

    const int tid = threadIdx.x;
    const int tx = tid & 15;       // output col group
    const int ty = tid >> 4;       // output row group
    const int bm = blockIdx.x * 64;
    const int bn = blockIdx.y * 64;

    const int arow = tid >> 2;         // 0..63
    const int acol = (tid & 3) << 2;   // 0,4,8,12
    const int brow = tid >> 4;         // 0..15
    const int bcol = (tid & 15) << 2;  // 0..60

    float acc[4][4] = {};

    for (int k0 = 0; k0 < K; k0 += 16) {
        const float4 a4 = *(const float4*)(A + (size_t)(bm + arow) * K + k0 + acol);
        const float4 b4 = *(const float4*)(B + (size_t)(k0 + brow) * N + bn + bcol);
        As[arow][acol + 0] = a4.x;
        As[arow][acol + 1] = a4.y;
        As[arow][acol + 2] = a4.z;
        As[arow][acol + 3] = a4.w;
        *(float4*)&Bs[brow][bcol] = b4;
        __syncthreads();

        #pragma unroll
        for (int kk = 0; kk < 16; ++kk) {
            const float a0 = As[ty * 4 + 0][kk];
            const float a1 = As[ty * 4 + 1][kk];
            const float a2 = As[ty * 4 + 2][kk];
            const float a3 = As[ty * 4 + 3][kk];
            const float4 b = *(const float4*)&Bs[kk][tx * 4];
            acc[0][0] = fmaf(a0, b.x, acc[0][0]); acc[0][1] = fmaf(a0, b.y, acc[0][1]);
            acc[0][2] = fmaf(a0, b.z, acc[0][2]); acc[0][3] = fmaf(a0, b.w, acc[0][3]);
            acc[1][0] = fmaf(a1, b.x, acc[1][0]); acc[1][1] = fmaf(a1, b.y, acc[1][1]);
            acc[1][2] = fmaf(a1, b.z, acc[1][2]); acc[1][3] = fmaf(a1, b.w, acc[1][3]);
            acc[2][0] = fmaf(a2, b.x, acc[2][0]); acc[2][1] = fmaf(a2, b.y, acc[2][1]);
            acc[2][2] = fmaf(a2, b.z, acc[2][2]); acc[2][3] = fmaf(a2, b.w, acc[2][3]);
            acc[3][0] = fmaf(a3, b.x, acc[3][0]); acc[3][1] = fmaf(a3, b.y, acc[3][1]);
            acc[3][2] = fmaf(a3, b.z, acc[3][2]); acc[3][3] = fmaf(a3, b.w, acc[3][3]);
        }
        __syncthreads();
    }

    float4 bb = {0.f, 0.f, 0.f, 0.f};
    if (bias) bb = *(const float4*)(bias + bn + tx * 4);
    #pragma unroll
    for (int i = 0; i < 4; ++i) {
        float4 o;
        o.x = acc[i][0] + bb.x;
        o.y = acc[i][1] + bb.y;
        o.z = acc[i][2] + bb.z;
        o.w = acc[i][3] + bb.w;
        *(float4*)(C + (size_t)(bm + ty * 4 + i) * N + bn + tx * 4) = o;
    }
}

// ---------------------------------------------------------------------------
// Local 7x7 window attention over (T=4, H=32, W=32), 8 heads, hd=48.
// qkv layout: [N][3*384] rows; q at col head*48, k at 384+head*48, v at 768+head*48.
// Zero-padded (NOT masked) out-of-bounds keys: score 0 enters the softmax.
// One thread per (query position, head): block = (t,h), 256 thr = 8 heads x 32 w.
// ---------------------------------------------------------------------------
__global__ __launch_bounds__(256) void local_attn(const float* __restrict__ qkv,
                                                  float* __restrict__ out)
{
    const int th = blockIdx.x;       // t*32 + h
    const int t = th >> 5;
    const int h = th & 31;
    const int head = threadIdx.x >> 5;
    const int w = threadIdx.x & 31;
    const int n = (th << 5) | w;     // t*1024 + h*32 + w
    const float scale = 0.14433756729740643f;  // 48^-0.5

    const float* qp = qkv + (size_t)n * C3 + head * HD;
    float q[HD];
    #pragma unroll
    for (int d = 0; d < HD; d += 4) {
        const float4 v4 = *(const float4*)(qp + d);
        q[d] = v4.x; q[d + 1] = v4.y; q[d + 2] = v4.z; q[d + 3] = v4.w;
    }

    float s[49];
    #pragma unroll
    for (int dy = 0; dy < 7; ++dy) {
        const int hk = h + dy - 3;
        #pragma unroll
        for (int dx = 0; dx < 7; ++dx) {
            const int wk = w + dx - 3;
            float acc = 0.f;
            if ((unsigned)hk < 32u && (unsigned)wk < 32u) {
                const int nk = ((t * 32 + hk) << 5) | wk;
                const float* kp = qkv + (size_t)nk * C3 + (C_DIM + head * HD);
                #pragma unroll
                for (int d = 0; d < HD; d += 4) {
                    const float4 kv = *(const float4*)(kp + d);
                    acc = fmaf(q[d],     kv.x, acc);
                    acc = fmaf(q[d + 1], kv.y, acc);
                    acc = fmaf(q[d + 2], kv.z, acc);
                    acc = fmaf(q[d + 3], kv.w, acc);
                }
                acc *= scale;
            }
            s[dy * 7 + dx] = acc;   // OOB -> 0, matches zero-padding semantics
        }
    }

    float m = s[0];
    #pragma unroll
    for (int p = 1; p < 49; ++p) m = fmaxf(m, s[p]);
    float sum = 0.f;
    #pragma unroll
    for (int p = 0; p < 49; ++p) { s[p] = __expf(s[p] - m); sum += s[p]; }
    const float inv = 1.f / sum;    // denominator includes OOB exp(0-m) terms

    float o[HD] = {};
    #pragma unroll
    for (int dy = 0; dy < 7; ++dy) {
        const int hk = h + dy - 3;
        #pragma unroll
        for (int dx = 0; dx < 7; ++dx) {
            const int wk = w + dx - 3;
            if ((unsigned)hk < 32u && (unsigned)wk < 32u) {   // OOB v == 0: skip
                const float wgt = s[dy * 7 + dx] * inv;
                const int nk = ((t * 32 + hk) << 5) | wk;
                const float* vp = qkv + (size_t)nk * C3 + (2 * C_DIM + head * HD);
                #pragma unroll
                for (int d = 0; d < HD; d += 4) {
                    const float4 vv = *(const float4*)(vp + d);
                    o[d]     = fmaf(wgt, vv.x, o[d]);
                    o[d + 1] = fmaf(wgt, vv.y, o[d + 1]);
                    o[d + 2] = fmaf(wgt, vv.z, o[d + 2]);
                    o[d + 3] = fmaf(wgt, vv.w, o[d + 3]);
                }
            }
        }
    }

    float* op = out + (size_t)n * C_DIM + head * HD;
    #pragma unroll
    for (int d = 0; d < HD; d += 4) {
        const float4 v4 = { o[d], o[d + 1], o[d + 2], o[d + 3] };
        *(float4*)(op + d) = v4;
    }
}

extern "C" void kernel_launch(void* const* d_in, const int* in_sizes, int n_in,
                              void* d_out, int out_size, void* d_ws, size_t ws_size,
                              hipStream_t stream)
{
    const float* x      = (const float*)d_in[0];
    const float* w_qkv  = (const float*)d_in[1];
    const float* w_proj = (const float*)d_in[2];
    const float* b_proj = (const float*)d_in[3];
    // inputs 4,5 are H=32, W=32 (python ints) — geometry hardcoded to match.

    const int M = 4096;
    float* qkv = (float*)d_ws;                      // 4096 x 1152
    float* att = qkv + (size_t)M * C3;              // 4096 x 384

    dim3 blk(256);
    // qkv = x @ w_qkv
    gemm64<<<dim3(M / 64, C3 / 64), blk, 0, stream>>>(x, w_qkv, nullptr, qkv, M, C3, C_DIM);
    // local window attention
    local_attn<<<dim3(128), blk, 0, stream>>>(qkv, att);
    // out = att @ w_proj + b_proj
    gemm64<<<dim3(M / 64, C_DIM / 64), blk, 0, stream>>>(att, w_proj, b_proj, (float*)d_out, M, C_DIM, C_DIM);
}

// Round 5
// 145.984 us; speedup vs baseline: 1.4894x; 1.4894x over previous
//
#include <hip/hip_runtime.h>
#include <math.h>

#define NH 8
#define HD 48
#define C_DIM 384
#define C3 1152

// ---------------------------------------------------------------------------
// Tiled fp32 GEMM: C[M,N] = A[M,K] * B[K,N] (+ bias per column, optional)
// BM=BN=64, BK=16, 256 threads, 4x4 micro-tile per thread.
// ---------------------------------------------------------------------------
__global__ __launch_bounds__(256) void gemm64(const float* __restrict__ A,
                                              const float* __restrict__ B,
                                              const float* __restrict__ bias,
                                              float* __restrict__ C,
                                              int M, int N, int K)
{
    __shared__ float As[64][17];   // +1 pad breaks bank-conflict on column reads
    __shared__ float Bs[16][64];

    const int tid = threadIdx.x;
    const int tx = tid & 15;       // output col group
    const int ty = tid >> 4;       // output row group
    const int bm = blockIdx.x * 64;
    const int bn = blockIdx.y * 64;

    const int arow = tid >> 2;         // 0..63
    const int acol = (tid & 3) << 2;   // 0,4,8,12
    const int brow = tid >> 4;         // 0..15
    const int bcol = (tid & 15) << 2;  // 0..60

    float acc[4][4] = {};

    for (int k0 = 0; k0 < K; k0 += 16) {
        const float4 a4 = *(const float4*)(A + (size_t)(bm + arow) * K + k0 + acol);
        const float4 b4 = *(const float4*)(B + (size_t)(k0 + brow) * N + bn + bcol);
        As[arow][acol + 0] = a4.x;
        As[arow][acol + 1] = a4.y;
        As[arow][acol + 2] = a4.z;
        As[arow][acol + 3] = a4.w;
        *(float4*)&Bs[brow][bcol] = b4;
        __syncthreads();

        #pragma unroll
        for (int kk = 0; kk < 16; ++kk) {
            const float a0 = As[ty * 4 + 0][kk];
            const float a1 = As[ty * 4 + 1][kk];
            const float a2 = As[ty * 4 + 2][kk];
            const float a3 = As[ty * 4 + 3][kk];
            const float4 b = *(const float4*)&Bs[kk][tx * 4];
            acc[0][0] = fmaf(a0, b.x, acc[0][0]); acc[0][1] = fmaf(a0, b.y, acc[0][1]);
            acc[0][2] = fmaf(a0, b.z, acc[0][2]); acc[0][3] = fmaf(a0, b.w, acc[0][3]);
            acc[1][0] = fmaf(a1, b.x, acc[1][0]); acc[1][1] = fmaf(a1, b.y, acc[1][1]);
            acc[1][2] = fmaf(a1, b.z, acc[1][2]); acc[1][3] = fmaf(a1, b.w, acc[1][3]);
            acc[2][0] = fmaf(a2, b.x, acc[2][0]); acc[2][1] = fmaf(a2, b.y, acc[2][1]);
            acc[2][2] = fmaf(a2, b.z, acc[2][2]); acc[2][3] = fmaf(a2, b.w, acc[2][3]);
            acc[3][0] = fmaf(a3, b.x, acc[3][0]); acc[3][1] = fmaf(a3, b.y, acc[3][1]);
            acc[3][2] = fmaf(a3, b.z, acc[3][2]); acc[3][3] = fmaf(a3, b.w, acc[3][3]);
        }
        __syncthreads();
    }

    float4 bb = {0.f, 0.f, 0.f, 0.f};
    if (bias) bb = *(const float4*)(bias + bn + tx * 4);
    #pragma unroll
    for (int i = 0; i < 4; ++i) {
        float4 o;
        o.x = acc[i][0] + bb.x;
        o.y = acc[i][1] + bb.y;
        o.z = acc[i][2] + bb.z;
        o.w = acc[i][3] + bb.w;
        *(float4*)(C + (size_t)(bm + ty * 4 + i) * N + bn + tx * 4) = o;
    }
}

// ---------------------------------------------------------------------------
// Local 7x7 window attention, lane-cooperative version.
// 16 lanes per (query n, head); lane dlane owns d = {dlane, dlane+16, dlane+32}.
// gid = n*8 + head  ->  4 head-groups per wave share the same n (h,w), so
// validity branches are wave-uniform and the 4 groups' K-row loads form one
// 768B contiguous segment (heads adjacent within the qkv row).
// Zero-padded (NOT masked) OOB keys: score 0 enters the softmax denominator.
// ---------------------------------------------------------------------------
__global__ __launch_bounds__(256) void local_attn16(const float* __restrict__ qkv,
                                                    float* __restrict__ out)
{
    const int tid = threadIdx.x;
    const int dlane = tid & 15;
    const int gid = blockIdx.x * 16 + (tid >> 4);
    const int head = gid & 7;
    const int n = gid >> 3;              // 0..4095
    const int t = n >> 10;
    const int h = (n >> 5) & 31;
    const int w = n & 31;
    const float scale = 0.14433756729740643f;  // 48^-0.5

    // Q fragment: 3 floats, strided by 16 so each load instr is 64B contiguous
    const float* qp = qkv + (size_t)n * C3 + head * HD;
    const float q0 = qp[dlane];
    const float q1 = qp[dlane + 16];
    const float q2 = qp[dlane + 32];

    const size_t base_k = (size_t)(C_DIM + head * HD);
    const size_t base_v = (size_t)(2 * C_DIM + head * HD);

    float s[49];
    #pragma unroll
    for (int p = 0; p < 49; ++p) {
        const int dy = p / 7, dx = p % 7;
        const int hk = h + dy - 3;
        const int wk = w + dx - 3;
        float sc = 0.f;
        if ((unsigned)hk < 32u && (unsigned)wk < 32u) {     // wave-uniform
            const int nk = (t << 10) | (hk << 5) | wk;
            const float* kp = qkv + (size_t)nk * C3 + base_k;
            float acc = q0 * kp[dlane];
            acc = fmaf(q1, kp[dlane + 16], acc);
            acc = fmaf(q2, kp[dlane + 32], acc);
            // reduce across the 16-lane group (DPP-speed xor shuffles)
            acc += __shfl_xor(acc, 1, 16);
            acc += __shfl_xor(acc, 2, 16);
            acc += __shfl_xor(acc, 4, 16);
            acc += __shfl_xor(acc, 8, 16);
            sc = acc * scale;
        }
        s[p] = sc;   // OOB -> 0, matches zero-padding semantics
    }

    // softmax over 49 slots (computed redundantly in all 16 lanes, no comm)
    float m = s[0];
    #pragma unroll
    for (int p = 1; p < 49; ++p) m = fmaxf(m, s[p]);
    float sum = 0.f;
    #pragma unroll
    for (int p = 0; p < 49; ++p) { s[p] = __expf(s[p] - m); sum += s[p]; }
    const float inv = 1.f / sum;   // denominator includes OOB exp(0-m) terms

    float o0 = 0.f, o1 = 0.f, o2 = 0.f;
    #pragma unroll
    for (int p = 0; p < 49; ++p) {
        const int dy = p / 7, dx = p % 7;
        const int hk = h + dy - 3;
        const int wk = w + dx - 3;
        if ((unsigned)hk < 32u && (unsigned)wk < 32u) {     // OOB v == 0: skip
            const float wgt = s[p] * inv;
            const int nk = (t << 10) | (hk << 5) | wk;
            const float* vp = qkv + (size_t)nk * C3 + base_v;
            o0 = fmaf(wgt, vp[dlane],      o0);
            o1 = fmaf(wgt, vp[dlane + 16], o1);
            o2 = fmaf(wgt, vp[dlane + 32], o2);
        }
    }

    float* op = out + (size_t)n * C_DIM + head * HD;
    op[dlane]      = o0;
    op[dlane + 16] = o1;
    op[dlane + 32] = o2;
}

extern "C" void kernel_launch(void* const* d_in, const int* in_sizes, int n_in,
                              void* d_out, int out_size, void* d_ws, size_t ws_size,
                              hipStream_t stream)
{
    const float* x      = (const float*)d_in[0];
    const float* w_qkv  = (const float*)d_in[1];
    const float* w_proj = (const float*)d_in[2];
    const float* b_proj = (const float*)d_in[3];
    // inputs 4,5 are H=32, W=32 (python ints) — geometry hardcoded to match.

    const int M = 4096;
    float* qkv = (float*)d_ws;                      // 4096 x 1152
    float* att = qkv + (size_t)M * C3;              // 4096 x 384

    dim3 blk(256);
    // qkv = x @ w_qkv
    gemm64<<<dim3(M / 64, C3 / 64), blk, 0, stream>>>(x, w_qkv, nullptr, qkv, M, C3, C_DIM);
    // local window attention: 4096*8 (query,head) groups, 16 groups/block
    local_attn16<<<dim3(2048), blk, 0, stream>>>(qkv, att);
    // out = att @ w_proj + b_proj
    gemm64<<<dim3(M / 64, C_DIM / 64), blk, 0, stream>>>(att, w_proj, b_proj, (float*)d_out, M, C_DIM, C_DIM);
}

// Round 7
// 113.841 us; speedup vs baseline: 1.9100x; 1.2823x over previous
//
#include <hip/hip_runtime.h>
#include <hip/hip_bf16.h>
#include <math.h>

#define NH 8
#define HD 48
#define C_DIM 384
#define C3 1152

typedef unsigned short ushort_t;
typedef __attribute__((ext_vector_type(8))) short short8;
typedef __attribute__((ext_vector_type(4))) float f32x4;

// ---------------------------------------------------------------------------
// fp32 -> bf16 (hi, lo) elementwise split:  x ~= hi + lo, each bf16.
// ---------------------------------------------------------------------------
__global__ __launch_bounds__(256) void split_bf16_kernel(const float* __restrict__ in,
                                                         ushort_t* __restrict__ hi,
                                                         ushort_t* __restrict__ lo,
                                                         int n4)
{
    const int i = blockIdx.x * 256 + threadIdx.x;
    if (i >= n4) return;
    const float4 v = ((const float4*)in)[i];
    const float f[4] = {v.x, v.y, v.z, v.w};
    ushort_t hb[4], lb[4];
    #pragma unroll
    for (int j = 0; j < 4; ++j) {
        __hip_bfloat16 h = __float2bfloat16(f[j]);
        __hip_bfloat16 l = __float2bfloat16(f[j] - __bfloat162float(h));
        hb[j] = *(ushort_t*)&h;
        lb[j] = *(ushort_t*)&l;
    }
    *(ushort4*)(hi + i * 4) = make_ushort4(hb[0], hb[1], hb[2], hb[3]);
    *(ushort4*)(lo + i * 4) = make_ushort4(lb[0], lb[1], lb[2], lb[3]);
}

// ---------------------------------------------------------------------------
// fp32 W[K][N] -> transposed bf16 splits WT_hi[N][K], WT_lo[N][K].
// (Transposed so GEMM B-fragments are contiguous along K.)
// ---------------------------------------------------------------------------
__global__ __launch_bounds__(256) void split_wT_kernel(const float* __restrict__ w,
                                                       ushort_t* __restrict__ hiT,
                                                       ushort_t* __restrict__ loT,
                                                       int K, int N)
{
    const int idx = blockIdx.x * 256 + threadIdx.x;
    if (idx >= K * N) return;
    const int k = idx / N;
    const int n = idx - k * N;
    const float v = w[idx];
    __hip_bfloat16 h = __float2bfloat16(v);
    __hip_bfloat16 l = __float2bfloat16(v - __bfloat162float(h));
    hiT[n * K + k] = *(ushort_t*)&h;
    loT[n * K + k] = *(ushort_t*)&l;
}

// ---------------------------------------------------------------------------
// Split-precision MFMA GEMM: C = (Ah+Al)(Bh+Bl) ~= AhBh + AhBl + AlBh  (fp32-
// equivalent accuracy; AlBl ~ 2^-18 rel, dropped).  A*: [M][K] bf16 row-major,
// B*T: [N][K] bf16 (transposed weights).  Tile 128x64, BK=32, 4 waves, each
// wave 64x32 via 4x2 frags of v_mfma_f32_16x16x32_bf16.
// LDS rows padded 32->40 elems (80B stride): 16-lane frag reads hit 2-way
// bank aliasing only (free per m136); unpadded 64B stride would be 8-way.
// ---------------------------------------------------------------------------
__global__ __launch_bounds__(256) void gemm_mfma3(const ushort_t* __restrict__ Ah,
                                                  const ushort_t* __restrict__ Al,
                                                  const ushort_t* __restrict__ BhT,
                                                  const ushort_t* __restrict__ BlT,
                                                  const float* __restrict__ bias,
                                                  float* __restrict__ C,
                                                  int N, int K)
{
    __shared__ ushort_t sAh[128 * 40];
    __shared__ ushort_t sAl[128 * 40];
    __shared__ ushort_t sBh[64 * 40];
    __shared__ ushort_t sBl[64 * 40];

    const int tid = threadIdx.x;
    const int bm = blockIdx.x * 128;
    const int bn = blockIdx.y * 64;

    // staging: A tiles 128 rows x 4 16B-chunks (2 chunks/thread), B tiles 64x4 (1/thread)
    const int rowA = tid >> 2;            // 0..63 (+64 for second chunk)
    const int slotA = (tid & 3) * 8;      // element offset within row
    const int rowB = tid >> 2;
    const int slotB = (tid & 3) * 8;

    const ushort_t* gAh0 = Ah + (size_t)(bm + rowA) * K + slotA;
    const ushort_t* gAh1 = Ah + (size_t)(bm + rowA + 64) * K + slotA;
    const ushort_t* gAl0 = Al + (size_t)(bm + rowA) * K + slotA;
    const ushort_t* gAl1 = Al + (size_t)(bm + rowA + 64) * K + slotA;
    const ushort_t* gBh  = BhT + (size_t)(bn + rowB) * K + slotB;
    const ushort_t* gBl  = BlT + (size_t)(bn + rowB) * K + slotB;

    const int lane = tid & 63;
    const int wid = tid >> 6;
    const int wm = wid >> 1;              // 0..1
    const int wn = wid & 1;               // 0..1
    const int fr = lane & 15;             // frag row (A) / col (B)
    const int kb = lane >> 4;             // 0..3 k-block
    const int aoff = (wm * 64 + fr) * 40 + kb * 8;
    const int boff = (wn * 32 + fr) * 40 + kb * 8;

    f32x4 acc[4][2] = {};

    for (int k0 = 0; k0 < K; k0 += 32) {
        const short8 va0 = *(const short8*)(gAh0 + k0);
        const short8 va1 = *(const short8*)(gAh1 + k0);
        const short8 vl0 = *(const short8*)(gAl0 + k0);
        const short8 vl1 = *(const short8*)(gAl1 + k0);
        const short8 vb0 = *(const short8*)(gBh + k0);
        const short8 vb1 = *(const short8*)(gBl + k0);
        *(short8*)&sAh[rowA * 40 + slotA]        = va0;
        *(short8*)&sAh[(rowA + 64) * 40 + slotA] = va1;
        *(short8*)&sAl[rowA * 40 + slotA]        = vl0;
        *(short8*)&sAl[(rowA + 64) * 40 + slotA] = vl1;
        *(short8*)&sBh[rowB * 40 + slotB]        = vb0;
        *(short8*)&sBl[rowB * 40 + slotB]        = vb1;
        __syncthreads();

        short8 ah[4], al[4], bh[2], bl[2];
        #pragma unroll
        for (int m = 0; m < 4; ++m) {
            ah[m] = *(const short8*)&sAh[aoff + m * 16 * 40];
            al[m] = *(const short8*)&sAl[aoff + m * 16 * 40];
        }
        #pragma unroll
        for (int n = 0; n < 2; ++n) {
            bh[n] = *(const short8*)&sBh[boff + n * 16 * 40];
            bl[n] = *(const short8*)&sBl[boff + n * 16 * 40];
        }
        #pragma unroll
        for (int m = 0; m < 4; ++m) {
            #pragma unroll
            for (int n = 0; n < 2; ++n) {
                acc[m][n] = __builtin_amdgcn_mfma_f32_16x16x32_bf16(ah[m], bh[n], acc[m][n], 0, 0, 0);
                acc[m][n] = __builtin_amdgcn_mfma_f32_16x16x32_bf16(ah[m], bl[n], acc[m][n], 0, 0, 0);
                acc[m][n] = __builtin_amdgcn_mfma_f32_16x16x32_bf16(al[m], bh[n], acc[m][n], 0, 0, 0);
            }
        }
        __syncthreads();
    }

    // epilogue: C/D layout col = lane&15, row = (lane>>4)*4 + reg  [m89-verified]
    #pragma unroll
    for (int n = 0; n < 2; ++n) {
        const int col = bn + wn * 32 + n * 16 + fr;
        const float bv = bias ? bias[col] : 0.f;
        #pragma unroll
        for (int m = 0; m < 4; ++m) {
            const int r0 = bm + wm * 64 + m * 16 + kb * 4;
            #pragma unroll
            for (int r = 0; r < 4; ++r) {
                C[(size_t)(r0 + r) * N + col] = acc[m][n][r] + bv;
            }
        }
    }
}

// ---------------------------------------------------------------------------
// fp32 fallback GEMM (used only if ws_size too small for the MFMA path).
// ---------------------------------------------------------------------------
__global__ __launch_bounds__(256) void gemm64(const float* __restrict__ A,
                                              const float* __restrict__ B,
                                              const float* __restrict__ bias,
                                              float* __restrict__ C,
                                              int M, int N, int K)
{
    __shared__ float As[64][17];
    __shared__ float Bs[16][64];

    const int tid = threadIdx.x;
    const int tx = tid & 15;
    const int ty = tid >> 4;
    const int bm = blockIdx.x * 64;
    const int bn = blockIdx.y * 64;
    const int arow = tid >> 2;
    const int acol = (tid & 3) << 2;
    const int brow = tid >> 4;
    const int bcol = (tid & 15) << 2;

    float acc[4][4] = {};

    for (int k0 = 0; k0 < K; k0 += 16) {
        const float4 a4 = *(const float4*)(A + (size_t)(bm + arow) * K + k0 + acol);
        const float4 b4 = *(const float4*)(B + (size_t)(k0 + brow) * N + bn + bcol);
        As[arow][acol + 0] = a4.x; As[arow][acol + 1] = a4.y;
        As[arow][acol + 2] = a4.z; As[arow][acol + 3] = a4.w;
        *(float4*)&Bs[brow][bcol] = b4;
        __syncthreads();
        #pragma unroll
        for (int kk = 0; kk < 16; ++kk) {
            const float a0 = As[ty * 4 + 0][kk];
            const float a1 = As[ty * 4 + 1][kk];
            const float a2 = As[ty * 4 + 2][kk];
            const float a3 = As[ty * 4 + 3][kk];
            const float4 b = *(const float4*)&Bs[kk][tx * 4];
            acc[0][0] = fmaf(a0, b.x, acc[0][0]); acc[0][1] = fmaf(a0, b.y, acc[0][1]);
            acc[0][2] = fmaf(a0, b.z, acc[0][2]); acc[0][3] = fmaf(a0, b.w, acc[0][3]);
            acc[1][0] = fmaf(a1, b.x, acc[1][0]); acc[1][1] = fmaf(a1, b.y, acc[1][1]);
            acc[1][2] = fmaf(a1, b.z, acc[1][2]); acc[1][3] = fmaf(a1, b.w, acc[1][3]);
            acc[2][0] = fmaf(a2, b.x, acc[2][0]); acc[2][1] = fmaf(a2, b.y, acc[2][1]);
            acc[2][2] = fmaf(a2, b.z, acc[2][2]); acc[2][3] = fmaf(a2, b.w, acc[2][3]);
            acc[3][0] = fmaf(a3, b.x, acc[3][0]); acc[3][1] = fmaf(a3, b.y, acc[3][1]);
            acc[3][2] = fmaf(a3, b.z, acc[3][2]); acc[3][3] = fmaf(a3, b.w, acc[3][3]);
        }
        __syncthreads();
    }

    float4 bb = {0.f, 0.f, 0.f, 0.f};
    if (bias) bb = *(const float4*)(bias + bn + tx * 4);
    #pragma unroll
    for (int i = 0; i < 4; ++i) {
        float4 o;
        o.x = acc[i][0] + bb.x; o.y = acc[i][1] + bb.y;
        o.z = acc[i][2] + bb.z; o.w = acc[i][3] + bb.w;
        *(float4*)(C + (size_t)(bm + ty * 4 + i) * N + bn + tx * 4) = o;
    }
}

// ---------------------------------------------------------------------------
// Local 7x7 window attention, lane-cooperative (16 lanes per query-head).
// Zero-padded (NOT masked) OOB keys: score 0 enters the softmax denominator.
// ---------------------------------------------------------------------------
__global__ __launch_bounds__(256) void local_attn16(const float* __restrict__ qkv,
                                                    float* __restrict__ out)
{
    const int tid = threadIdx.x;
    const int dlane = tid & 15;
    const int gid = blockIdx.x * 16 + (tid >> 4);
    const int head = gid & 7;
    const int n = gid >> 3;
    const int t = n >> 10;
    const int h = (n >> 5) & 31;
    const int w = n & 31;
    const float scale = 0.14433756729740643f;  // 48^-0.5

    const float* qp = qkv + (size_t)n * C3 + head * HD;
    const float q0 = qp[dlane];
    const float q1 = qp[dlane + 16];
    const float q2 = qp[dlane + 32];

    const size_t base_k = (size_t)(C_DIM + head * HD);
    const size_t base_v = (size_t)(2 * C_DIM + head * HD);

    float s[49];
    #pragma unroll
    for (int p = 0; p < 49; ++p) {
        const int dy = p / 7, dx = p % 7;
        const int hk = h + dy - 3;
        const int wk = w + dx - 3;
        float sc = 0.f;
        if ((unsigned)hk < 32u && (unsigned)wk < 32u) {
            const int nk = (t << 10) | (hk << 5) | wk;
            const float* kp = qkv + (size_t)nk * C3 + base_k;
            float acc = q0 * kp[dlane];
            acc = fmaf(q1, kp[dlane + 16], acc);
            acc = fmaf(q2, kp[dlane + 32], acc);
            acc += __shfl_xor(acc, 1, 16);
            acc += __shfl_xor(acc, 2, 16);
            acc += __shfl_xor(acc, 4, 16);
            acc += __shfl_xor(acc, 8, 16);
            sc = acc * scale;
        }
        s[p] = sc;
    }

    float m = s[0];
    #pragma unroll
    for (int p = 1; p < 49; ++p) m = fmaxf(m, s[p]);
    float sum = 0.f;
    #pragma unroll
    for (int p = 0; p < 49; ++p) { s[p] = __expf(s[p] - m); sum += s[p]; }
    const float inv = 1.f / sum;

    float o0 = 0.f, o1 = 0.f, o2 = 0.f;
    #pragma unroll
    for (int p = 0; p < 49; ++p) {
        const int dy = p / 7, dx = p % 7;
        const int hk = h + dy - 3;
        const int wk = w + dx - 3;
        if ((unsigned)hk < 32u && (unsigned)wk < 32u) {
            const float wgt = s[p] * inv;
            const int nk = (t << 10) | (hk << 5) | wk;
            const float* vp = qkv + (size_t)nk * C3 + base_v;
            o0 = fmaf(wgt, vp[dlane],      o0);
            o1 = fmaf(wgt, vp[dlane + 16], o1);
            o2 = fmaf(wgt, vp[dlane + 32], o2);
        }
    }

    float* op = out + (size_t)n * C_DIM + head * HD;
    op[dlane]      = o0;
    op[dlane + 16] = o1;
    op[dlane + 32] = o2;
}

extern "C" void kernel_launch(void* const* d_in, const int* in_sizes, int n_in,
                              void* d_out, int out_size, void* d_ws, size_t ws_size,
                              hipStream_t stream)
{
    const float* x      = (const float*)d_in[0];
    const float* w_qkv  = (const float*)d_in[1];
    const float* w_proj = (const float*)d_in[2];
    const float* b_proj = (const float*)d_in[3];

    const int M = 4096;
    dim3 blk(256);

    // ws layout (bytes):
    //   qkv fp32   [4096x1152] @ 0         (18,874,368)
    //   att fp32   [4096x384]  @ 18874368  ( 6,291,456)
    //   Ah  bf16   [4096x384]  @ 25165824  ( 3,145,728)  x_hi, then att_hi
    //   Al  bf16   [4096x384]  @ 28311552  ( 3,145,728)
    //   BhT bf16   [1152x384]  @ 31457280  (   884,736)  wT_hi (qkv then proj)
    //   BlT bf16   [1152x384]  @ 32342016  (   884,736)
    const size_t NEED = 33226752;

    unsigned char* ws = (unsigned char*)d_ws;
    float* qkv = (float*)ws;
    float* att = (float*)(ws + 18874368);

    if (ws_size >= NEED) {
        ushort_t* Ah  = (ushort_t*)(ws + 25165824);
        ushort_t* Al  = (ushort_t*)(ws + 28311552);
        ushort_t* BhT = (ushort_t*)(ws + 31457280);
        ushort_t* BlT = (ushort_t*)(ws + 32342016);

        split_bf16_kernel<<<dim3(1536), blk, 0, stream>>>(x, Ah, Al, M * C_DIM / 4);
        split_wT_kernel<<<dim3((C_DIM * C3 + 255) / 256), blk, 0, stream>>>(w_qkv, BhT, BlT, C_DIM, C3);
        gemm_mfma3<<<dim3(M / 128, C3 / 64), blk, 0, stream>>>(Ah, Al, BhT, BlT, nullptr, qkv, C3, C_DIM);

        local_attn16<<<dim3(2048), blk, 0, stream>>>(qkv, att);

        split_bf16_kernel<<<dim3(1536), blk, 0, stream>>>(att, Ah, Al, M * C_DIM / 4);
        split_wT_kernel<<<dim3((C_DIM * C_DIM + 255) / 256), blk, 0, stream>>>(w_proj, BhT, BlT, C_DIM, C_DIM);
        gemm_mfma3<<<dim3(M / 128, C_DIM / 64), blk, 0, stream>>>(Ah, Al, BhT, BlT, b_proj, (float*)d_out, C_DIM, C_DIM);
    } else {
        // fallback: proven fp32 path (round-5 kernel)
        gemm64<<<dim3(M / 64, C3 / 64), blk, 0, stream>>>(x, w_qkv, nullptr, qkv, M, C3, C_DIM);
        local_attn16<<<dim3(2048), blk, 0, stream>>>(qkv, att);
        gemm64<<<dim3(M / 64, C_DIM / 64), blk, 0, stream>>>(att, w_proj, b_proj, (float*)d_out, M, C_DIM, C_DIM);
    }
}